// Round 1
// baseline (2540.857 us; speedup 1.0000x reference)
//
#include <hip/hip_runtime.h>
#include <cstdint>

#define NTOK 49
#define CDIM 192
#define NH 6
#define HD 32
#define PROW 52   // padded attn-row stride (16B aligned, bank-friendly)

__device__ __forceinline__ float dot4(const float4 a, const float4 b) {
    return a.x * b.x + a.y * b.y + a.z * b.z + a.w * b.w;
}

__global__ __launch_bounds__(256)
void winattn_fused(const float* __restrict__ x,
                   const float* __restrict__ mask,
                   const float* __restrict__ qkv_w,
                   const float* __restrict__ qkv_b,
                   const float* __restrict__ proj_w,
                   const float* __restrict__ proj_b,
                   const float* __restrict__ rpb,
                   const int* __restrict__ rel_idx,
                   float* __restrict__ out)
{
    // 4 x 37632 B = 150528 B LDS -> 1 block/CU
    __shared__ float xs[NTOK * CDIM];   // x tile; reused as P[3][49][PROW] logits
    __shared__ float qs[NTOK * CDIM];   // q; reused as attention output (n, h*32+d)
    __shared__ float ks_[NTOK * CDIM];
    __shared__ float vs[NTOK * CDIM];

    const int b   = blockIdx.x;
    const int tid = threadIdx.x;
    const int w   = b & 63;
    const float scale = 0.17677669529663687f;  // 32^-0.5

    // ---- stage x ----
    {
        const float4* xg = (const float4*)(x + (size_t)b * (NTOK * CDIM));
        float4* xl = (float4*)xs;
        for (int idx = tid; idx < NTOK * CDIM / 4; idx += 256)
            xl[idx] = xg[idx];
    }
    __syncthreads();

    // ---- QKV GEMM: C[49x576] = xs[49x192] @ W^T + b ----
    {
        const int ct = tid & 31;   // column lane
        const int rt = tid >> 5;   // row group 0..7
        int roff[7];
        bool rvalid[7];
        #pragma unroll
        for (int m = 0; m < 7; ++m) {
            const int r = rt + 8 * m;
            rvalid[m] = (r < NTOK);
            roff[m] = (r < NTOK ? r : NTOK - 1) * CDIM;  // clamp: no OOB, discarded on store
        }
        for (int p = 0; p < 9; ++p) {
            const int c0 = p * 64 + ct * 2;
            const float4* w0 = (const float4*)(qkv_w + (size_t)c0 * CDIM);
            const float4* w1 = (const float4*)(qkv_w + (size_t)(c0 + 1) * CDIM);
            float acc0[7], acc1[7];
            const float bb0 = qkv_b[c0], bb1 = qkv_b[c0 + 1];
            #pragma unroll
            for (int m = 0; m < 7; ++m) { acc0[m] = bb0; acc1[m] = bb1; }
            #pragma unroll 2
            for (int k4 = 0; k4 < CDIM / 4; ++k4) {
                const float4 wa = w0[k4];
                const float4 wb = w1[k4];
                #pragma unroll
                for (int m = 0; m < 7; ++m) {
                    const float4 xv = *(const float4*)&xs[roff[m] + k4 * 4];
                    acc0[m] += dot4(xv, wa);
                    acc1[m] += dot4(xv, wb);
                }
            }
            float* dst = (p < 3) ? qs : (p < 6 ? ks_ : vs);
            const int cl = (p % 3) * 64 + ct * 2;
            #pragma unroll
            for (int m = 0; m < 7; ++m) {
                if (rvalid[m]) {
                    dst[(rt + 8 * m) * CDIM + cl]     = acc0[m];
                    dst[(rt + 8 * m) * CDIM + cl + 1] = acc1[m];
                }
            }
        }
    }

    float* P = xs;  // logits buffer overlays xs: rows [hh*49+i], stride PROW

    for (int hb = 0; hb < 2; ++hb) {
        __syncthreads();  // qkv stores done / previous PV done with P

        // ---- QK^T + rel-pos bias + window mask ----
        if (tid < 3 * NTOK) {
            const int hh = tid / NTOK;
            const int i  = tid - hh * NTOK;
            const int h  = hb * 3 + hh;
            float4 qreg[8];
            #pragma unroll
            for (int u = 0; u < 8; ++u)
                qreg[u] = *(const float4*)&qs[i * CDIM + h * HD + u * 4];
            const float* mrow = mask + ((size_t)w * NTOK + i) * NTOK;
            const int*   rrow = rel_idx + i * NTOK;
            float* prow = &P[(hh * NTOK + i) * PROW];
            for (int j = 0; j < NTOK; ++j) {
                float acc = 0.f;
                #pragma unroll
                for (int u = 0; u < 8; ++u) {
                    const float4 kv = *(const float4*)&ks_[j * CDIM + h * HD + u * 4];
                    acc += dot4(qreg[u], kv);
                }
                prow[j] = acc * scale + rpb[rrow[j] * NH + h] + mrow[j];
            }
        }
        __syncthreads();

        // ---- row softmax ----
        if (tid < 3 * NTOK) {
            float* prow = &P[tid * PROW];
            float mx = prow[0];
            for (int j = 1; j < NTOK; ++j) mx = fmaxf(mx, prow[j]);
            float s = 0.f;
            for (int j = 0; j < NTOK; ++j) { const float e = __expf(prow[j] - mx); prow[j] = e; s += e; }
            const float inv = 1.0f / s;
            for (int j = 0; j < NTOK; ++j) prow[j] *= inv;
        }
        __syncthreads();

        // ---- PV: out[i][h*32+d] = sum_j P[i][j] * v[j][h*32+d]  -> write into qs ----
        {
            const int d0 = (tid & 7) * 4;
            const int ig = tid >> 3;       // 0..31
            const int i1 = ig + 32;
            const bool has1 = (i1 < NTOK);
            #pragma unroll
            for (int hh = 0; hh < 3; ++hh) {
                const int h = hb * 3 + hh;
                const float* p0 = &P[(hh * NTOK + ig) * PROW];
                const float* p1 = &P[(hh * NTOK + i1) * PROW];  // in-LDS-bounds even when i1>=49
                float a00 = 0, a01 = 0, a02 = 0, a03 = 0;
                float a10 = 0, a11 = 0, a12 = 0, a13 = 0;
                for (int j = 0; j < 48; j += 4) {
                    const float4 pa = *(const float4*)&p0[j];
                    const float4 pb = *(const float4*)&p1[j];
                    #pragma unroll
                    for (int jj = 0; jj < 4; ++jj) {
                        const float4 vv = *(const float4*)&vs[(j + jj) * CDIM + h * HD + d0];
                        const float fa = (&pa.x)[jj];
                        const float fb = (&pb.x)[jj];
                        a00 += fa * vv.x; a01 += fa * vv.y; a02 += fa * vv.z; a03 += fa * vv.w;
                        a10 += fb * vv.x; a11 += fb * vv.y; a12 += fb * vv.z; a13 += fb * vv.w;
                    }
                }
                {   // tail j = 48
                    const float4 vv = *(const float4*)&vs[48 * CDIM + h * HD + d0];
                    const float fa = p0[48];
                    const float fb = p1[48];
                    a00 += fa * vv.x; a01 += fa * vv.y; a02 += fa * vv.z; a03 += fa * vv.w;
                    a10 += fb * vv.x; a11 += fb * vv.y; a12 += fb * vv.z; a13 += fb * vv.w;
                }
                *(float4*)&qs[ig * CDIM + h * HD + d0] = make_float4(a00, a01, a02, a03);
                if (has1)
                    *(float4*)&qs[i1 * CDIM + h * HD + d0] = make_float4(a10, a11, a12, a13);
            }
        }
    }
    __syncthreads();

    // ---- proj GEMM: out[49x192] = qs[49x192] @ proj_w^T + proj_b ----
    {
        const int ct = tid & 31;
        const int rt = tid >> 5;
        int roff[7];
        bool rvalid[7];
        #pragma unroll
        for (int m = 0; m < 7; ++m) {
            const int r = rt + 8 * m;
            rvalid[m] = (r < NTOK);
            roff[m] = (r < NTOK ? r : NTOK - 1) * CDIM;
        }
        float* og = out + (size_t)b * (NTOK * CDIM);
        for (int p = 0; p < 3; ++p) {
            const int c0 = p * 64 + ct * 2;
            const float4* w0 = (const float4*)(proj_w + (size_t)c0 * CDIM);
            const float4* w1 = (const float4*)(proj_w + (size_t)(c0 + 1) * CDIM);
            float acc0[7], acc1[7];
            const float bb0 = proj_b[c0], bb1 = proj_b[c0 + 1];
            #pragma unroll
            for (int m = 0; m < 7; ++m) { acc0[m] = bb0; acc1[m] = bb1; }
            #pragma unroll 2
            for (int k4 = 0; k4 < CDIM / 4; ++k4) {
                const float4 wa = w0[k4];
                const float4 wb = w1[k4];
                #pragma unroll
                for (int m = 0; m < 7; ++m) {
                    const float4 xv = *(const float4*)&qs[roff[m] + k4 * 4];
                    acc0[m] += dot4(xv, wa);
                    acc1[m] += dot4(xv, wb);
                }
            }
            #pragma unroll
            for (int m = 0; m < 7; ++m) {
                if (rvalid[m]) {
                    og[(rt + 8 * m) * CDIM + c0]     = acc0[m];
                    og[(rt + 8 * m) * CDIM + c0 + 1] = acc1[m];
                }
            }
        }
    }
}

extern "C" void kernel_launch(void* const* d_in, const int* in_sizes, int n_in,
                              void* d_out, int out_size, void* d_ws, size_t ws_size,
                              hipStream_t stream) {
    const float* x      = (const float*)d_in[0];
    const float* mask   = (const float*)d_in[1];
    const float* qkv_w  = (const float*)d_in[2];
    const float* qkv_b  = (const float*)d_in[3];
    const float* proj_w = (const float*)d_in[4];
    const float* proj_b = (const float*)d_in[5];
    const float* rpb    = (const float*)d_in[6];
    const int*   rel    = (const int*)d_in[7];

    const int nwin = in_sizes[0] / (NTOK * CDIM);  // 4096
    winattn_fused<<<nwin, 256, 0, stream>>>(x, mask, qkv_w, qkv_b, proj_w, proj_b,
                                            rpb, rel, (float*)d_out);
}

// Round 3
// 701.228 us; speedup vs baseline: 3.6234x; 3.6234x over previous
//
#include <hip/hip_runtime.h>

typedef unsigned short u16;
typedef unsigned int   u32;
typedef __bf16 bf16x8 __attribute__((ext_vector_type(8)));
typedef float  f32x4  __attribute__((ext_vector_type(4)));

#define NTOK 49
#define CDIM 192
#define NH   6
#define HD   32

// ---- LDS arena layout (u16 units) ----
#define QOFF   0
#define QSTR   200            // 400 B row stride -> 2-way bank alias (free)
#define KOFF   9800
#define VTOFF  19600
#define VTSTR  56             // 112 B -> 2-way
#define SPOFF  30352          // x staging (49x200) overlays P (3 heads x 49 x 72)
#define SPSTR  72             // 144 B, 16B-aligned rows
#define SPH    (49*72)
#define ARENA_U16 40936       // 81,872 B -> exactly 2 blocks/CU

// ---- ws layout (u16 units); total 2.43 MB ----
#define WS_QH 0
#define WS_QL 110592
#define WS_PH 221184
#define WS_PL (221184+36864)
#define WS_BM (221184+73728)

__device__ __forceinline__ u16 f2bf(float f) {
    union { float f; u32 u; } v; v.f = f;
    u32 u = v.u;
    u += 0x7fffu + ((u >> 16) & 1u);   // RNE
    return (u16)(u >> 16);
}
__device__ __forceinline__ float bf2f(u16 h) {
    union { u32 u; float f; } v; v.u = ((u32)h) << 16;
    return v.f;
}

// ---------------- prep kernels ----------------
__global__ void prep_weights(const float* __restrict__ qkv_w,
                             const float* __restrict__ proj_w,
                             u16* __restrict__ ws)
{
    const int idx = blockIdx.x * 256 + threadIdx.x;
    if (idx < 110592) {
        const float f = qkv_w[idx];
        const u16 hi = f2bf(f);
        ws[WS_QH + idx] = hi;
        ws[WS_QL + idx] = f2bf(f - bf2f(hi));
    } else if (idx < 147456) {
        const int j = idx - 110592;
        const float f = proj_w[j];
        const u16 hi = f2bf(f);
        ws[WS_PH + j] = hi;
        ws[WS_PL + j] = f2bf(f - bf2f(hi));
    }
}

__global__ void prep_bm(const float* __restrict__ mask,
                        const float* __restrict__ rpb,
                        const int*   __restrict__ rel,
                        u16* __restrict__ ws)
{
    const int idx = blockIdx.x * 256 + threadIdx.x;   // [win][h][i][j]
    if (idx >= 64 * NH * NTOK * NTOK) return;
    const int j = idx % 49;
    int t = idx / 49;
    const int i = t % 49;  t /= 49;
    const int h = t % NH;
    const int w = t / NH;
    const float v = rpb[rel[i * 49 + j] * NH + h] + mask[((size_t)w * 49 + i) * 49 + j];
    ws[WS_BM + idx] = f2bf(v);
}

// ---------------- fused QKV + attention + proj ----------------
__global__ __launch_bounds__(256, 2)
void winattn_core(const float* __restrict__ x,
                  const float* __restrict__ qkv_b,
                  const float* __restrict__ proj_b,
                  const u16* __restrict__ ws,
                  float* __restrict__ out)
{
    __shared__ u16 arena[ARENA_U16];
    const int b    = blockIdx.x;
    const int tid  = threadIdx.x;
    const int lane = tid & 63;
    const int wv   = tid >> 6;
    const int l15  = lane & 15;
    const int lg   = lane >> 4;
    const int win  = b & 63;

    // ---- stage x -> bf16 in sP region; zero the V^T pad (j=49..55) ----
    {
        const float4* xg = (const float4*)(x + (size_t)b * (NTOK * CDIM));
        for (int i = tid; i < NTOK * CDIM / 4; i += 256) {
            const float4 v = xg[i];
            const int row = (i * 4) / CDIM, col = (i * 4) % CDIM;
            u16* dst = &arena[SPOFF + row * QSTR + col];
            *(u32*)dst       = (u32)f2bf(v.x) | ((u32)f2bf(v.y) << 16);
            *(u32*)(dst + 2) = (u32)f2bf(v.z) | ((u32)f2bf(v.w) << 16);
        }
        for (int i = tid; i < CDIM * 7; i += 256)
            arena[VTOFF + (i / 7) * VTSTR + 49 + (i % 7)] = 0;   // kill 0*NaN in PV
    }
    __syncthreads();

    // ---- QKV GEMM: 36 N-tiles of 16, waves split N (9 each, 3 triples) ----
    {
        const u16* wh = ws + WS_QH;
        const u16* wl = ws + WS_QL;
        int arow[4];
        #pragma unroll
        for (int m = 0; m < 4; ++m) {
            const int r = 16 * m + l15;
            arow[m] = (r < NTOK ? r : NTOK - 1) * QSTR;   // clamp: garbage rows discarded
        }
        for (int tr = 0; tr < 3; ++tr) {
            const int ntb = wv * 9 + tr * 3;
            f32x4 acc[3][4] = {};
            for (int k6 = 0; k6 < 6; ++k6) {
                const int k0 = k6 * 32;
                bf16x8 A[4];
                #pragma unroll
                for (int m = 0; m < 4; ++m)
                    A[m] = *(const bf16x8*)&arena[SPOFF + arow[m] + k0 + 8 * lg];
                #pragma unroll
                for (int jt = 0; jt < 3; ++jt) {
                    const int gcol = (ntb + jt) * 16 + l15;
                    const size_t wo = (size_t)gcol * CDIM + k0 + 8 * lg;
                    const bf16x8 Bh = *(const bf16x8*)&wh[wo];
                    const bf16x8 Bl = *(const bf16x8*)&wl[wo];
                    #pragma unroll
                    for (int m = 0; m < 4; ++m) {
                        acc[jt][m] = __builtin_amdgcn_mfma_f32_16x16x32_bf16(A[m], Bh, acc[jt][m], 0, 0, 0);
                        acc[jt][m] = __builtin_amdgcn_mfma_f32_16x16x32_bf16(A[m], Bl, acc[jt][m], 0, 0, 0);
                    }
                }
            }
            // epilogue: D row = 16m+4lg+r, col = l15 -> q/k row-major, v transposed
            #pragma unroll
            for (int jt = 0; jt < 3; ++jt) {
                const int gcol = (ntb + jt) * 16 + l15;
                const float bias = qkv_b[gcol];
                const int sec = gcol / CDIM;
                const int cw  = gcol % CDIM;
                #pragma unroll
                for (int m = 0; m < 4; ++m) {
                    #pragma unroll
                    for (int r = 0; r < 4; ++r) {
                        const int i = 16 * m + 4 * lg + r;
                        if (i < NTOK) {
                            const u16 hv = f2bf(acc[jt][m][r] + bias);
                            if (sec == 0)      arena[QOFF + i * QSTR + cw] = hv;
                            else if (sec == 1) arena[KOFF + i * QSTR + cw] = hv;
                            else               arena[VTOFF + cw * VTSTR + i] = hv;
                        }
                    }
                }
            }
        }
    }

    const float scale = 0.17677669529663687f;
    const int i0 = 16 * wv;                       // wave's M-tile (output rows)
    const int qrow = (i0 + l15 < NTOK ? i0 + l15 : NTOK - 1);
    const u16* bmw = ws + WS_BM + (size_t)win * NH * NTOK * NTOK;

    for (int hb = 0; hb < 2; ++hb) {
        __syncthreads();    // qkv ready / previous phase done with sP
        #pragma unroll
        for (int h3 = 0; h3 < 3; ++h3) {
            const int h = hb * 3 + h3;
            // QK^T: one K-step (d=32)
            const bf16x8 Aq = *(const bf16x8*)&arena[QOFF + qrow * QSTR + h * HD + 8 * lg];
            f32x4 pacc[4];
            #pragma unroll
            for (int jt = 0; jt < 4; ++jt) {
                const int kr = (jt * 16 + l15 < NTOK ? jt * 16 + l15 : NTOK - 1);
                const bf16x8 Bk = *(const bf16x8*)&arena[KOFF + kr * QSTR + h * HD + 8 * lg];
                f32x4 z = {};
                pacc[jt] = __builtin_amdgcn_mfma_f32_16x16x32_bf16(Aq, Bk, z, 0, 0, 0);
            }
            // bias+mask, row softmax (row lives in one 16-lane group at reg r)
            const u16* bmh = bmw + (size_t)h * NTOK * NTOK;
            #pragma unroll
            for (int r = 0; r < 4; ++r) {
                const int i  = i0 + 4 * lg + r;
                const int ic = i < NTOK ? i : NTOK - 1;
                float val[4];
                #pragma unroll
                for (int jt = 0; jt < 4; ++jt) {
                    const int j = jt * 16 + l15;
                    val[jt] = (j < NTOK) ? pacc[jt][r] * scale + bf2f(bmh[ic * 49 + j])
                                         : -1e30f;
                }
                float mx = fmaxf(fmaxf(val[0], val[1]), fmaxf(val[2], val[3]));
                mx = fmaxf(mx, __shfl_xor(mx, 1));
                mx = fmaxf(mx, __shfl_xor(mx, 2));
                mx = fmaxf(mx, __shfl_xor(mx, 4));
                mx = fmaxf(mx, __shfl_xor(mx, 8));
                float s = 0.f;
                #pragma unroll
                for (int jt = 0; jt < 4; ++jt) { val[jt] = __expf(val[jt] - mx); s += val[jt]; }
                s += __shfl_xor(s, 1); s += __shfl_xor(s, 2);
                s += __shfl_xor(s, 4); s += __shfl_xor(s, 8);
                const float inv = 1.0f / s;
                if (i < NTOK) {                          // j>=49 lanes write exact zeros (K-pad)
                    #pragma unroll
                    for (int jt = 0; jt < 4; ++jt)
                        arena[SPOFF + h3 * SPH + i * SPSTR + jt * 16 + l15] = f2bf(val[jt] * inv);
                }
            }
        }
        __syncthreads();    // P visible; also: all waves done reading Q cols of this hb
        #pragma unroll
        for (int h3 = 0; h3 < 3; ++h3) {
            const int h = hb * 3 + h3;
            const bf16x8 Ap0 = *(const bf16x8*)&arena[SPOFF + h3 * SPH + qrow * SPSTR + 8 * lg];
            const bf16x8 Ap1 = *(const bf16x8*)&arena[SPOFF + h3 * SPH + qrow * SPSTR + 32 + 8 * lg];
            #pragma unroll
            for (int nt = 0; nt < 2; ++nt) {
                const int vrow = h * HD + nt * 16 + l15;
                const int jb1 = (32 + 8 * lg < VTSTR) ? 32 + 8 * lg : 48;  // clamped pad read; pad zeroed
                const bf16x8 Bv0 = *(const bf16x8*)&arena[VTOFF + vrow * VTSTR + 8 * lg];
                const bf16x8 Bv1 = *(const bf16x8*)&arena[VTOFF + vrow * VTSTR + jb1];
                f32x4 acc = {};
                acc = __builtin_amdgcn_mfma_f32_16x16x32_bf16(Ap0, Bv0, acc, 0, 0, 0);
                acc = __builtin_amdgcn_mfma_f32_16x16x32_bf16(Ap1, Bv1, acc, 0, 0, 0);
                // attnout (bf16) -> Q region (cols of this hb are dead now)
                #pragma unroll
                for (int r = 0; r < 4; ++r) {
                    const int i = i0 + 4 * lg + r;
                    if (i < NTOK)
                        arena[QOFF + i * QSTR + h * HD + nt * 16 + l15] = f2bf(acc[r]);
                }
            }
        }
    }

    // ---- proj GEMM: out[49x192] = attnout(Q region) @ proj_w^T + b ----
    // A rows are this wave's own M-tile (written by this wave in PV) -> no barrier needed.
    {
        const u16* ph = ws + WS_PH;
        const u16* pl = ws + WS_PL;
        float* og = out + (size_t)b * (NTOK * CDIM);
        bf16x8 A[6];
        #pragma unroll
        for (int k6 = 0; k6 < 6; ++k6)
            A[k6] = *(const bf16x8*)&arena[QOFF + (i0 + l15) * QSTR + k6 * 32 + 8 * lg];
        for (int nt = 0; nt < 12; ++nt) {
            const int gcol = nt * 16 + l15;
            f32x4 acc = {};
            #pragma unroll
            for (int k6 = 0; k6 < 6; ++k6) {
                const size_t wo = (size_t)gcol * CDIM + k6 * 32 + 8 * lg;
                const bf16x8 Bh = *(const bf16x8*)&ph[wo];
                const bf16x8 Bl = *(const bf16x8*)&pl[wo];
                acc = __builtin_amdgcn_mfma_f32_16x16x32_bf16(A[k6], Bh, acc, 0, 0, 0);
                acc = __builtin_amdgcn_mfma_f32_16x16x32_bf16(A[k6], Bl, acc, 0, 0, 0);
            }
            const float bias = proj_b[gcol];
            #pragma unroll
            for (int r = 0; r < 4; ++r) {
                const int i = i0 + 4 * lg + r;
                if (i < NTOK)
                    og[(size_t)i * CDIM + gcol] = acc[r] + bias;
            }
        }
    }
}

extern "C" void kernel_launch(void* const* d_in, const int* in_sizes, int n_in,
                              void* d_out, int out_size, void* d_ws, size_t ws_size,
                              hipStream_t stream) {
    const float* x      = (const float*)d_in[0];
    const float* mask   = (const float*)d_in[1];
    const float* qkv_w  = (const float*)d_in[2];
    const float* qkv_b  = (const float*)d_in[3];
    const float* proj_w = (const float*)d_in[4];
    const float* proj_b = (const float*)d_in[5];
    const float* rpb    = (const float*)d_in[6];
    const int*   rel    = (const int*)d_in[7];
    u16* ws = (u16*)d_ws;

    const int nwin = in_sizes[0] / (NTOK * CDIM);          // 4096
    const int bm_n = 64 * NH * NTOK * NTOK;

    prep_weights<<<576, 256, 0, stream>>>(qkv_w, proj_w, ws);
    prep_bm<<<(bm_n + 255) / 256, 256, 0, stream>>>(mask, rpb, rel, ws);
    winattn_core<<<nwin, 256, 0, stream>>>(x, qkv_b, proj_b, ws, (float*)d_out);
}

// Round 4
// 270.971 us; speedup vs baseline: 9.3768x; 2.5878x over previous
//
#include <hip/hip_runtime.h>

typedef unsigned short u16;
typedef unsigned int   u32;
typedef _Float16 f16x8 __attribute__((ext_vector_type(8)));
typedef float    f32x4 __attribute__((ext_vector_type(4)));

#define NTOK 49
#define CDIM 192
#define NH   6
#define HD   32

// ---- LDS arena (u16 units) ----
#define QOFF   0
#define QSTR   200            // 400 B stride
#define KOFF   9800
#define VTOFF  19600
#define VTSTR  56
#define SPOFF  30352          // x staging overlays P
#define SPSTR  72
#define SPH    (NTOK*SPSTR)
#define ARENA_U16 40936       // 81,872 B -> 2 blocks/CU

// ---- ws layout (u16 units) ----
#define WS_WQ 0               // qkv weights, frag-major: [(t*6+k6)*512 + lane*8 + e]
#define WS_WP 110592          // proj weights, same scheme (12 tiles)
#define WS_BM 147456          // bias+mask: [w][h][i][j(64)], pad j>=49 = -inf

static __device__ __forceinline__ u16 f2h(float f){ union{ _Float16 h; u16 u;} v; v.h=(_Float16)f; return v.u; }
static __device__ __forceinline__ float h2f(u16 u){ union{ u16 u; _Float16 h;} v; v.u=u; return (float)v.h; }

// ---------------- prep ----------------
__global__ void prep_weights(const float* __restrict__ qkv_w,
                             const float* __restrict__ proj_w,
                             u16* __restrict__ ws)
{
    const int idx = blockIdx.x*256 + threadIdx.x;
    if (idx < 110592) {
        const int fid = idx >> 9, r = idx & 511;
        const int lane = r >> 3, e = r & 7;
        const int t = fid/6, k6 = fid - 6*t;
        const int col = t*16 + (lane & 15);
        const int kk  = k6*32 + (lane >> 4)*8 + e;
        ws[WS_WQ + idx] = f2h(qkv_w[col*CDIM + kk]);
    } else if (idx < 147456) {
        const int j = idx - 110592;
        const int fid = j >> 9, r = j & 511;
        const int lane = r >> 3, e = r & 7;
        const int t = fid/6, k6 = fid - 6*t;
        const int col = t*16 + (lane & 15);
        const int kk  = k6*32 + (lane >> 4)*8 + e;
        ws[WS_WP + j] = f2h(proj_w[col*CDIM + kk]);
    }
}

__global__ void prep_bm(const float* __restrict__ mask,
                        const float* __restrict__ rpb,
                        const int*   __restrict__ rel,
                        u16* __restrict__ ws)
{
    const int idx = blockIdx.x*256 + threadIdx.x;
    if (idx >= 64*NH*NTOK*64) return;
    const int j = idx & 63;
    const int i = (idx >> 6) % NTOK;
    const int h = (idx/(64*NTOK)) % NH;
    const int w =  idx/(64*NTOK*NH);
    float v = -1e30f;   // -> fp16 -inf in pad columns
    if (j < NTOK)
        v = rpb[rel[i*NTOK+j]*NH + h] + mask[((size_t)w*NTOK+i)*NTOK + j];
    ws[WS_BM + idx] = f2h(v);
}

// ---------------- fused core ----------------
#define LDFRAG(B, BASE, t) { const u16* _p = (BASE) + (size_t)(t)*3072 + lane*8;      \
    B[0]=*(const f16x8*)(_p);      B[1]=*(const f16x8*)(_p+512);                      \
    B[2]=*(const f16x8*)(_p+1024); B[3]=*(const f16x8*)(_p+1536);                     \
    B[4]=*(const f16x8*)(_p+2048); B[5]=*(const f16x8*)(_p+2560); }

#define QKV_STEP(s, CUR, NXT, PF) {                                                   \
    if (PF) LDFRAG(NXT, wq, t0+(s)+2);                                                \
    f32x4 acc[4] = {};                                                                \
    _Pragma("unroll") for (int _k=0;_k<6;++_k)                                        \
      _Pragma("unroll") for (int _m=0;_m<4;++_m)                                      \
        acc[_m] = __builtin_amdgcn_mfma_f32_16x16x32_f16(A[_k][_m], CUR[_k], acc[_m],0,0,0); \
    const int _t = t0+(s); const int _gc = _t*16 + l15;                               \
    const int _sec = _t/12; const int _cw = _gc - _sec*CDIM;                          \
    _Pragma("unroll") for (int _m=0;_m<4;++_m)                                        \
      _Pragma("unroll") for (int _r=0;_r<4;++_r) {                                    \
        const int _i = 16*_m + 4*lg + _r;                                             \
        if (_i < NTOK) { const u16 _hv = f2h(acc[_m][_r] + qb[s]);                    \
          if (_sec==0)      arena[QOFF + _i*QSTR + _cw] = _hv;                        \
          else if (_sec==1) arena[KOFF + _i*QSTR + _cw] = _hv;                        \
          else              arena[VTOFF + _cw*VTSTR + _i] = _hv; } } }

#define PROJ_STEP(s, CUR, NXT, PF) {                                                  \
    if (PF) LDFRAG(NXT, wp, p0+(s)+1);                                                \
    f32x4 acc[4] = {};                                                                \
    _Pragma("unroll") for (int _k=0;_k<6;++_k)                                        \
      _Pragma("unroll") for (int _m=0;_m<4;++_m)                                      \
        acc[_m] = __builtin_amdgcn_mfma_f32_16x16x32_f16(PA[_k][_m], CUR[_k], acc[_m],0,0,0); \
    const int _gc = (p0+(s))*16 + l15;                                                \
    _Pragma("unroll") for (int _m=0;_m<4;++_m)                                        \
      _Pragma("unroll") for (int _r=0;_r<4;++_r) {                                    \
        const int _i = 16*_m + 4*lg + _r;                                             \
        if (_i < NTOK) og[(size_t)_i*CDIM + _gc] = acc[_m][_r] + pb[s]; } }

__global__ __launch_bounds__(256, 2)
void winattn_core(const float* __restrict__ x,
                  const float* __restrict__ qkv_b,
                  const float* __restrict__ proj_b,
                  const u16* __restrict__ ws,
                  float* __restrict__ out)
{
    __shared__ u16 arena[ARENA_U16];
    const int b    = blockIdx.x;
    const int tid  = threadIdx.x;
    const int lane = tid & 63;
    const int wv   = tid >> 6;
    const int l15  = lane & 15;
    const int lg   = lane >> 4;
    const int win  = b & 63;

    // ---- stage x -> fp16; zero V^T pad cols j=49..55 ----
    {
        const float4* xg = (const float4*)(x + (size_t)b * (NTOK * CDIM));
        for (int i = tid; i < NTOK * CDIM / 4; i += 256) {
            const float4 v = xg[i];
            const int row = (i * 4) / CDIM, col = (i * 4) % CDIM;
            u16* dst = &arena[SPOFF + row * QSTR + col];
            *(u32*)dst       = (u32)f2h(v.x) | ((u32)f2h(v.y) << 16);
            *(u32*)(dst + 2) = (u32)f2h(v.z) | ((u32)f2h(v.w) << 16);
        }
        for (int i = tid; i < CDIM * 7; i += 256)
            arena[VTOFF + (i / 7) * VTSTR + 49 + (i % 7)] = 0;
    }
    __syncthreads();

    // ---- QKV GEMM: A cached in regs, 3-deep B prefetch pipeline ----
    const u16* wq = ws + WS_WQ;
    int arow[4];
    #pragma unroll
    for (int m = 0; m < 4; ++m) {
        const int r = 16*m + l15;
        arow[m] = (r < NTOK ? r : NTOK-1) * QSTR;
    }
    const int t0 = wv * 9;
    {
        f16x8 Ba[6], Bb[6], Bc[6];
        LDFRAG(Ba, wq, t0); LDFRAG(Bb, wq, t0+1);
        float qb[9];
        #pragma unroll
        for (int s = 0; s < 9; ++s) qb[s] = qkv_b[(t0+s)*16 + l15];
        f16x8 A[6][4];
        #pragma unroll
        for (int k6 = 0; k6 < 6; ++k6)
            #pragma unroll
            for (int m = 0; m < 4; ++m)
                A[k6][m] = *(const f16x8*)&arena[SPOFF + arow[m] + k6*32 + 8*lg];

        QKV_STEP(0, Ba, Bc, 1)
        QKV_STEP(1, Bb, Ba, 1)
        QKV_STEP(2, Bc, Bb, 1)
        QKV_STEP(3, Ba, Bc, 1)
        QKV_STEP(4, Bb, Ba, 1)
        QKV_STEP(5, Bc, Bb, 1)
        QKV_STEP(6, Ba, Bc, 1)
        QKV_STEP(7, Bb, Ba, 0)
        QKV_STEP(8, Bc, Bb, 0)
    }

    // ---- attention ----
    const float scale = 0.17677669529663687f;
    const int i0 = 16 * wv;
    const int qrow = (i0 + l15 < NTOK ? i0 + l15 : NTOK-1);
    const u16* bmw = ws + WS_BM + (size_t)win * NH * NTOK * 64;

    for (int hb = 0; hb < 2; ++hb) {
        __syncthreads();    // qkv ready / previous PV done with sP
        #pragma unroll
        for (int h3 = 0; h3 < 3; ++h3) {
            const int h = hb*3 + h3;
            const u16* bmh = bmw + (size_t)h * NTOK * 64;
            u16 bmv[4][4];
            #pragma unroll
            for (int r = 0; r < 4; ++r) {
                const int i = i0 + 4*lg + r;
                const int ic = i < NTOK ? i : NTOK-1;
                #pragma unroll
                for (int jt = 0; jt < 4; ++jt)
                    bmv[r][jt] = bmh[ic*64 + jt*16 + l15];
            }
            const f16x8 Aq = *(const f16x8*)&arena[QOFF + qrow*QSTR + h*HD + 8*lg];
            f32x4 pacc[4];
            #pragma unroll
            for (int jt = 0; jt < 4; ++jt) {
                const int kr = (jt*16 + l15 < NTOK ? jt*16 + l15 : NTOK-1);
                const f16x8 Bk = *(const f16x8*)&arena[KOFF + kr*QSTR + h*HD + 8*lg];
                f32x4 z = {};
                pacc[jt] = __builtin_amdgcn_mfma_f32_16x16x32_f16(Aq, Bk, z, 0, 0, 0);
            }
            #pragma unroll
            for (int r = 0; r < 4; ++r) {
                const int i = i0 + 4*lg + r;
                float val[4];
                #pragma unroll
                for (int jt = 0; jt < 4; ++jt)
                    val[jt] = pacc[jt][r] * scale + h2f(bmv[r][jt]);
                float mx = fmaxf(fmaxf(val[0], val[1]), fmaxf(val[2], val[3]));
                mx = fmaxf(mx, __shfl_xor(mx, 1));
                mx = fmaxf(mx, __shfl_xor(mx, 2));
                mx = fmaxf(mx, __shfl_xor(mx, 4));
                mx = fmaxf(mx, __shfl_xor(mx, 8));
                float s = 0.f;
                #pragma unroll
                for (int jt = 0; jt < 4; ++jt) { val[jt] = __expf(val[jt] - mx); s += val[jt]; }
                s += __shfl_xor(s, 1); s += __shfl_xor(s, 2);
                s += __shfl_xor(s, 4); s += __shfl_xor(s, 8);
                const float inv = 1.0f / s;
                if (i < NTOK) {
                    #pragma unroll
                    for (int jt = 0; jt < 4; ++jt)
                        arena[SPOFF + h3*SPH + i*SPSTR + jt*16 + l15] = f2h(val[jt] * inv);
                }
            }
        }
        __syncthreads();    // P visible; all QK^T reads of this hb done
        #pragma unroll
        for (int h3 = 0; h3 < 3; ++h3) {
            const int h = hb*3 + h3;
            const f16x8 Ap0 = *(const f16x8*)&arena[SPOFF + h3*SPH + qrow*SPSTR + 8*lg];
            const f16x8 Ap1 = *(const f16x8*)&arena[SPOFF + h3*SPH + qrow*SPSTR + 32 + 8*lg];
            #pragma unroll
            for (int nt = 0; nt < 2; ++nt) {
                const int vrow = h*HD + nt*16 + l15;
                const int jb1 = (32 + 8*lg < VTSTR) ? 32 + 8*lg : 48;   // pad zeroed
                const f16x8 Bv0 = *(const f16x8*)&arena[VTOFF + vrow*VTSTR + 8*lg];
                const f16x8 Bv1 = *(const f16x8*)&arena[VTOFF + vrow*VTSTR + jb1];
                f32x4 acc = {};
                acc = __builtin_amdgcn_mfma_f32_16x16x32_f16(Ap0, Bv0, acc, 0, 0, 0);
                acc = __builtin_amdgcn_mfma_f32_16x16x32_f16(Ap1, Bv1, acc, 0, 0, 0);
                #pragma unroll
                for (int r = 0; r < 4; ++r) {
                    const int i = i0 + 4*lg + r;
                    if (i < NTOK)
                        arena[QOFF + i*QSTR + h*HD + nt*16 + l15] = f2h(acc[r]);
                }
            }
        }
    }

    // ---- proj: each wave = 3 N-tiles x all 64 rows; double-buffered B ----
    const u16* wp = ws + WS_WP;
    const int p0 = wv * 3;
    f16x8 Pa[6], Pb2[6];
    LDFRAG(Pa, wp, p0);                       // issue before barrier (global, no LDS dep)
    float pb[3];
    #pragma unroll
    for (int s = 0; s < 3; ++s) pb[s] = proj_b[(p0+s)*16 + l15];
    __syncthreads();                          // all attnout rows in LDS
    {
        f16x8 PA[6][4];
        #pragma unroll
        for (int k6 = 0; k6 < 6; ++k6)
            #pragma unroll
            for (int m = 0; m < 4; ++m)
                PA[k6][m] = *(const f16x8*)&arena[QOFF + arow[m] + k6*32 + 8*lg];
        float* og = out + (size_t)b * (NTOK * CDIM);
        PROJ_STEP(0, Pa, Pb2, 1)
        PROJ_STEP(1, Pb2, Pa, 1)
        PROJ_STEP(2, Pa, Pb2, 0)
    }
}

extern "C" void kernel_launch(void* const* d_in, const int* in_sizes, int n_in,
                              void* d_out, int out_size, void* d_ws, size_t ws_size,
                              hipStream_t stream) {
    const float* x      = (const float*)d_in[0];
    const float* mask   = (const float*)d_in[1];
    const float* qkv_w  = (const float*)d_in[2];
    const float* qkv_b  = (const float*)d_in[3];
    const float* proj_w = (const float*)d_in[4];
    const float* proj_b = (const float*)d_in[5];
    const float* rpb    = (const float*)d_in[6];
    const int*   rel    = (const int*)d_in[7];
    u16* ws = (u16*)d_ws;

    const int nwin = in_sizes[0] / (NTOK * CDIM);          // 4096
    prep_weights<<<576, 256, 0, stream>>>(qkv_w, proj_w, ws);
    prep_bm<<<(64*NH*NTOK*64 + 255)/256, 256, 0, stream>>>(mask, rpb, rel, ws);
    winattn_core<<<nwin, 256, 0, stream>>>(x, qkv_b, proj_b, ws, (float*)d_out);
}

// Round 6
// 188.110 us; speedup vs baseline: 13.5073x; 1.4405x over previous
//
#include <hip/hip_runtime.h>

typedef unsigned short u16;
typedef unsigned int   u32;
typedef _Float16 f16x8 __attribute__((ext_vector_type(8)));
typedef __fp16   hf2   __attribute__((ext_vector_type(2)));
typedef float    f32x4 __attribute__((ext_vector_type(4)));

#define NTOK 49
#define CDIM 192
#define NH   6
#define HD   32

// ---- LDS arena (u16 units) ----
#define QOFF   0
#define QSTR   200            // 400 B stride (stride%32dw==4 -> 2-way, free)
#define KOFF   9800
#define VTOFF  19600
#define VTSTR  56             // 112 B
#define XOFF   30352          // x staging 49x200; per-wave P ping-pong overlays
#define PSTR   72             // 144 B
#define ARENA_U16 40152       // 80,304 B -> 2 blocks/CU

// ---- ws layout (u16 units) ----
#define WS_WQ 0               // qkv weights frag-major: [(t*6+k6)*512 + lane*8 + e]
#define WS_WP 110592          // proj weights, same scheme
#define WS_BM 147456          // bias+mask per-thread: [w][h][tid(256)][jt(4)][r(4)]

static __device__ __forceinline__ u16 f2h(float f){ union{ _Float16 h; u16 u;} v; v.h=(_Float16)f; return v.u; }
static __device__ __forceinline__ u32 pk2(float a, float b){
    hf2 h = __builtin_amdgcn_cvt_pkrtz(a, b);
    return __builtin_bit_cast(u32, h);
}

// ---------------- prep ----------------
__global__ void prep_weights(const float* __restrict__ qkv_w,
                             const float* __restrict__ proj_w,
                             u16* __restrict__ ws)
{
    const int idx = blockIdx.x*256 + threadIdx.x;
    if (idx < 110592) {
        const int fid = idx >> 9, r = idx & 511;
        const int lane = r >> 3, e = r & 7;
        const int t = fid/6, k6 = fid - 6*t;
        const int col = t*16 + (lane & 15);
        const int kk  = k6*32 + (lane >> 4)*8 + e;
        ws[WS_WQ + idx] = f2h(qkv_w[col*CDIM + kk]);
    } else if (idx < 147456) {
        const int j = idx - 110592;
        const int fid = j >> 9, r = j & 511;
        const int lane = r >> 3, e = r & 7;
        const int t = fid/6, k6 = fid - 6*t;
        const int col = t*16 + (lane & 15);
        const int kk  = k6*32 + (lane >> 4)*8 + e;
        ws[WS_WP + j] = f2h(proj_w[col*CDIM + kk]);
    }
}

// per-thread layout: thread tid of wave wv handles q-row i=16*(tid>>6)+(tid&15),
// scores j = jt*16 + 4*((tid>>4)&3) + r
__global__ void prep_bm(const float* __restrict__ mask,
                        const float* __restrict__ rpb,
                        const int*   __restrict__ rel,
                        u16* __restrict__ ws)
{
    const int idx = blockIdx.x*256 + threadIdx.x;
    if (idx >= 64*NH*256*16) return;
    const int r   = idx & 3;
    const int jt  = (idx >> 2) & 3;
    const int tid = (idx >> 4) & 255;
    const int rest = idx >> 12;
    const int h = rest % NH;
    const int w = rest / NH;
    const int i  = 16*(tid >> 6) + (tid & 15);
    const int lg = (tid >> 4) & 3;
    const int j  = jt*16 + 4*lg + r;
    float v;
    if (i >= NTOK)      v = 0.0f;          // garbage rows: finite, discarded
    else if (j >= NTOK) v = -1e30f;        // -> f16 -inf, exp -> 0
    else v = rpb[rel[i*NTOK+j]*NH + h] + mask[((size_t)w*NTOK+i)*NTOK + j];
    ws[WS_BM + idx] = f2h(v);
}

// ---------------- fused core ----------------
#define LDFRAG(B, BASE, t) { const u16* _p = (BASE) + (size_t)(t)*3072 + lane*8;      \
    B[0]=*(const f16x8*)(_p);      B[1]=*(const f16x8*)(_p+512);                      \
    B[2]=*(const f16x8*)(_p+1024); B[3]=*(const f16x8*)(_p+1536);                     \
    B[4]=*(const f16x8*)(_p+2048); B[5]=*(const f16x8*)(_p+2560); }

#define QKV_STEP(s, CUR, NXT, PF) {                                                   \
    if (PF) LDFRAG(NXT, wq, t0+(s)+2);                                                \
    const int _t = t0+(s); const int _sec = _t/12; const int _cb = (_t - _sec*12)*16; \
    f32x4 _ac[4] = {};                                                                \
    if (_sec < 2) {  /* Q/K: swapped -> token=lane, 4 consecutive cols in regs */     \
      const float4 _b4 = *(const float4*)&qkv_b[_t*16 + 4*lg];                        \
      _Pragma("unroll") for (int _k=0;_k<6;++_k)                                      \
        _Pragma("unroll") for (int _m=0;_m<4;++_m)                                    \
          _ac[_m] = __builtin_amdgcn_mfma_f32_16x16x32_f16(CUR[_k], A[_k][_m], _ac[_m],0,0,0); \
      const float _sc = (_sec==0) ? 0.17677669529663687f : 1.0f;                      \
      u16* _dst = (_sec==0) ? (arena+QOFF) : (arena+KOFF);                            \
      _Pragma("unroll") for (int _m=0;_m<4;++_m) {                                    \
        const int _tok = 16*_m + l15;                                                 \
        if (_tok < NTOK) {                                                            \
          uint2 _wd = make_uint2(pk2((_ac[_m][0]+_b4.x)*_sc, (_ac[_m][1]+_b4.y)*_sc), \
                                 pk2((_ac[_m][2]+_b4.z)*_sc, (_ac[_m][3]+_b4.w)*_sc));\
          *(uint2*)&_dst[_tok*QSTR + _cb + 4*lg] = _wd; } }                           \
    } else {         /* V: normal -> consecutive tokens in regs -> packed V^T */      \
      const float _b1 = qkv_b[384 + _cb + l15];                                       \
      _Pragma("unroll") for (int _k=0;_k<6;++_k)                                      \
        _Pragma("unroll") for (int _m=0;_m<4;++_m)                                    \
          _ac[_m] = __builtin_amdgcn_mfma_f32_16x16x32_f16(A[_k][_m], CUR[_k], _ac[_m],0,0,0); \
      _Pragma("unroll") for (int _m=0;_m<4;++_m) {                                    \
        if (16*_m + 4*lg <= 48) {                                                     \
          uint2 _wd = make_uint2(pk2(_ac[_m][0]+_b1, _ac[_m][1]+_b1),                 \
                                 pk2(_ac[_m][2]+_b1, _ac[_m][3]+_b1));                \
          *(uint2*)&arena[VTOFF + (_cb + l15)*VTSTR + 16*_m + 4*lg] = _wd; } } } }

#define PROJ_STEP(s, CUR, NXT, PF) {                                                  \
    if (PF) LDFRAG(NXT, wp, p0+(s)+1);                                                \
    f32x4 _ac[4] = {};                                                                \
    _Pragma("unroll") for (int _k=0;_k<6;++_k)                                        \
      _Pragma("unroll") for (int _m=0;_m<4;++_m)                                      \
        _ac[_m] = __builtin_amdgcn_mfma_f32_16x16x32_f16(CUR[_k], PA[_k][_m], _ac[_m],0,0,0); \
    _Pragma("unroll") for (int _m=0;_m<4;++_m) {                                      \
      const int _tok = 16*_m + l15;                                                   \
      if (_tok < NTOK) {                                                              \
        float4 _o = make_float4(_ac[_m][0]+pb4[s].x, _ac[_m][1]+pb4[s].y,             \
                                _ac[_m][2]+pb4[s].z, _ac[_m][3]+pb4[s].w);            \
        *(float4*)&og[(size_t)_tok*CDIM + (p0+(s))*16 + 4*lg] = _o; } } }

__global__ __launch_bounds__(256, 2)
void winattn_core(const float* __restrict__ x,
                  const float* __restrict__ qkv_b,
                  const float* __restrict__ proj_b,
                  const u16* __restrict__ ws,
                  float* __restrict__ out)
{
    __shared__ __align__(16) u16 arena[ARENA_U16];
    const int b    = blockIdx.x;
    const int tid  = threadIdx.x;
    const int lane = tid & 63;
    const int wv   = tid >> 6;
    const int l15  = lane & 15;
    const int lg   = lane >> 4;
    const int win  = b & 63;

    // ---- stage x -> fp16 at XOFF; zero V^T pad cols 49..55 ----
    {
        const float4* xg = (const float4*)(x + (size_t)b * (NTOK * CDIM));
        for (int i = tid; i < NTOK * CDIM / 4; i += 256) {
            const float4 v = xg[i];
            const int row = (i * 4) / CDIM, col = (i * 4) % CDIM;
            *(uint2*)&arena[XOFF + row * QSTR + col] =
                make_uint2(pk2(v.x, v.y), pk2(v.z, v.w));
        }
        for (int i = tid; i < CDIM * 7; i += 256)
            arena[VTOFF + (i / 7) * VTSTR + 49 + (i % 7)] = 0;
    }
    __syncthreads();

    // ---- QKV GEMM ----
    const u16* wq = ws + WS_WQ;
    int arow[4];
    #pragma unroll
    for (int m = 0; m < 4; ++m) {
        const int r = 16*m + l15;
        arow[m] = (r < NTOK ? r : NTOK-1) * QSTR;
    }
    const int t0 = wv * 9;
    {
        f16x8 A[6][4];
        #pragma unroll
        for (int k6 = 0; k6 < 6; ++k6)
            #pragma unroll
            for (int m = 0; m < 4; ++m)
                A[k6][m] = *(const f16x8*)&arena[XOFF + arow[m] + k6*32 + 8*lg];
        f16x8 Ba[6], Bb[6], Bc[6];
        LDFRAG(Ba, wq, t0); LDFRAG(Bb, wq, t0+1);
        QKV_STEP(0, Ba, Bc, 1)
        QKV_STEP(1, Bb, Ba, 1)
        QKV_STEP(2, Bc, Bb, 1)
        QKV_STEP(3, Ba, Bc, 1)
        QKV_STEP(4, Bb, Ba, 1)
        QKV_STEP(5, Bc, Bb, 1)
        QKV_STEP(6, Ba, Bc, 1)
        QKV_STEP(7, Bb, Ba, 0)
        QKV_STEP(8, Bc, Bb, 0)
    }

    // ---- bm prefetch (global; before barrier) ----
    f16x8 bmf[6][2];
    {
        const u16* bmb = ws + WS_BM + (((size_t)win*NH)*256 + tid)*16;
        #pragma unroll
        for (int h = 0; h < NH; ++h) {
            bmf[h][0] = *(const f16x8*)(bmb + h*4096);
            bmf[h][1] = *(const f16x8*)(bmb + h*4096 + 8);
        }
    }
    __syncthreads();   // Q/K/VT visible

    // ---- attention: barrier-free; wave owns rows i0..i0+15 ----
    const int i0 = 16 * wv;
    const bool myok = (i0 + l15 < NTOK);
    const int myrow = myok ? i0 + l15 : NTOK-1;
    int krow[4];
    #pragma unroll
    for (int jt = 0; jt < 4; ++jt)
        krow[jt] = (jt*16 + l15 < NTOK ? jt*16 + l15 : NTOK-1) * QSTR;

    f16x8 Qf[6];
    #pragma unroll
    for (int h = 0; h < NH; ++h)
        Qf[h] = *(const f16x8*)&arena[QOFF + myrow*QSTR + h*HD + 8*lg];

    #pragma unroll
    for (int h = 0; h < NH; ++h) {
        u16* pp = arena + XOFF + wv*2336 + (h & 1)*1168;   // wave-private P ping-pong
        // QK^T swapped: D col=lane=i, regs=j
        f32x4 pacc[4];
        #pragma unroll
        for (int jt = 0; jt < 4; ++jt) {
            const f16x8 Kf = *(const f16x8*)&arena[KOFF + krow[jt] + h*HD + 8*lg];
            f32x4 z = {};
            pacc[jt] = __builtin_amdgcn_mfma_f32_16x16x32_f16(Kf, Qf[h], z, 0, 0, 0);
        }
        // softmax: 16 in-thread values + 2 shfls
        float val[4][4];
        float mx = -3e38f;
        #pragma unroll
        for (int jt = 0; jt < 4; ++jt)
            #pragma unroll
            for (int r = 0; r < 4; ++r) {
                val[jt][r] = pacc[jt][r] + (float)bmf[h][jt>>1][(jt&1)*4 + r];
                mx = fmaxf(mx, val[jt][r]);
            }
        mx = fmaxf(mx, __shfl_xor(mx, 16));
        mx = fmaxf(mx, __shfl_xor(mx, 32));
        float s = 0.f;
        #pragma unroll
        for (int jt = 0; jt < 4; ++jt)
            #pragma unroll
            for (int r = 0; r < 4; ++r) {
                const float e = __expf(val[jt][r] - mx);
                val[jt][r] = e; s += e;
            }
        s += __shfl_xor(s, 16);
        s += __shfl_xor(s, 32);
        const float inv = 1.0f / s;
        // P~ (unnormalized) -> private LDS, packed b64
        #pragma unroll
        for (int jt = 0; jt < 4; ++jt)
            *(uint2*)&pp[l15*PSTR + jt*16 + 4*lg] =
                make_uint2(pk2(val[jt][0], val[jt][1]), pk2(val[jt][2], val[jt][3]));
        // PV swapped: A=V^T, B=P; normalize at epilogue
        const f16x8 Pb0 = *(const f16x8*)&pp[l15*PSTR + 8*lg];
        const f16x8 Pb1 = *(const f16x8*)&pp[l15*PSTR + 32 + 8*lg];
        const int a1 = (32 + 8*lg <= 48) ? 32 + 8*lg : 48;   // clamp; P=0 kills pad
        #pragma unroll
        for (int nt = 0; nt < 2; ++nt) {
            const int vr = (h*HD + nt*16 + l15) * VTSTR;
            const f16x8 Va0 = *(const f16x8*)&arena[VTOFF + vr + 8*lg];
            const f16x8 Va1 = *(const f16x8*)&arena[VTOFF + vr + a1];
            f32x4 o = {};
            o = __builtin_amdgcn_mfma_f32_16x16x32_f16(Va0, Pb0, o, 0, 0, 0);
            o = __builtin_amdgcn_mfma_f32_16x16x32_f16(Va1, Pb1, o, 0, 0, 0);
            if (myok) {   // attnout -> dead Q region, own rows only
                *(uint2*)&arena[QOFF + (i0+l15)*QSTR + h*HD + nt*16 + 4*lg] =
                    make_uint2(pk2(o[0]*inv, o[1]*inv), pk2(o[2]*inv, o[3]*inv));
            }
        }
    }

    // ---- proj (swapped): issue B/bias loads before barrier ----
    const u16* wp = ws + WS_WP;
    const int p0 = wv * 3;
    f16x8 Pa[6], Pb2[6];
    LDFRAG(Pa, wp, p0);
    float4 pb4[3];
    #pragma unroll
    for (int s = 0; s < 3; ++s)
        pb4[s] = *(const float4*)&proj_b[(p0+s)*16 + 4*lg];
    __syncthreads();   // all attnout rows visible
    {
        f16x8 PA[6][4];
        #pragma unroll
        for (int k6 = 0; k6 < 6; ++k6)
            #pragma unroll
            for (int m = 0; m < 4; ++m)
                PA[k6][m] = *(const f16x8*)&arena[QOFF + arow[m] + k6*32 + 8*lg];
        float* og = out + (size_t)b * (NTOK * CDIM);
        PROJ_STEP(0, Pa, Pb2, 1)
        PROJ_STEP(1, Pb2, Pa, 1)
        PROJ_STEP(2, Pa, Pb2, 0)
    }
}

extern "C" void kernel_launch(void* const* d_in, const int* in_sizes, int n_in,
                              void* d_out, int out_size, void* d_ws, size_t ws_size,
                              hipStream_t stream) {
    const float* x      = (const float*)d_in[0];
    const float* mask   = (const float*)d_in[1];
    const float* qkv_w  = (const float*)d_in[2];
    const float* qkv_b  = (const float*)d_in[3];
    const float* proj_w = (const float*)d_in[4];
    const float* proj_b = (const float*)d_in[5];
    const float* rpb    = (const float*)d_in[6];
    const int*   rel    = (const int*)d_in[7];
    u16* ws = (u16*)d_ws;

    const int nwin = in_sizes[0] / (NTOK * CDIM);          // 4096
    prep_weights<<<576, 256, 0, stream>>>(qkv_w, proj_w, ws);
    prep_bm<<<(64*NH*256*16 + 255)/256, 256, 0, stream>>>(mask, rpb, rel, ws);
    winattn_core<<<nwin, 256, 0, stream>>>(x, qkv_b, proj_b, ws, (float*)d_out);
}